// Round 2
// baseline (537.425 us; speedup 1.0000x reference)
//
#include <hip/hip_runtime.h>

#define N_NODES 100000
#define N_EDGES 1000000
#define EPS 1e-5f
#define SLOPE 0.01f
#define NBLK 391   // ceil(N_NODES/256)
#define GBLK 1563  // ceil(N_NODES/64): 64 nodes/block, 5 threads/node, 320/block

// ---------------------------------------------------------------------------
// ws layout:
//   P        : E * 32 B (32 MB)  packed {float4 ef; int src; pad} per edge,
//                                ORIGINAL edge order (sequential write)
//   perm     : E ints   (4 MB)   edge id in CSR(dst) order
//   hist     : N ints   [zeroed] in-degree
//   cursor   : N ints   [zeroed] scatter cursor
//   stats    : 32 floats[zeroed] sum[16], sumsq[16]
//   row_part : N ints
//   bsum     : 512 ints
//   bsum_ex  : 512 ints
// ---------------------------------------------------------------------------

// Kernel 1: pack edge payload (seq, full-line writes) + in-degree histogram.
// 2 edges/thread.
__global__ __launch_bounds__(256) void pack_count_kernel(
    const float* __restrict__ efeat,
    const int* __restrict__ edge_index,
    int* __restrict__ hist,
    float4* __restrict__ P)
{
    int i = blockIdx.x * 256 + threadIdx.x;         // edge-pair id
    if (i >= N_EDGES / 2) return;
    int2 s = *(const int2*)(edge_index + 2 * i);
    int2 d = *(const int2*)(edge_index + N_EDGES + 2 * i);
    float4 e0 = *(const float4*)(efeat + (size_t)(2 * i) * 4);
    float4 e1 = *(const float4*)(efeat + (size_t)(2 * i) * 4 + 4);
    P[(size_t)4 * i + 0] = e0;
    P[(size_t)4 * i + 1] = make_float4(__int_as_float(s.x), 0.f, 0.f, 0.f);
    P[(size_t)4 * i + 2] = e1;
    P[(size_t)4 * i + 3] = make_float4(__int_as_float(s.y), 0.f, 0.f, 0.f);
    atomicAdd(hist + d.x, 1);
    atomicAdd(hist + d.y, 1);
}

// Kernel 2: block-local exclusive scan of hist + block sums.
__global__ __launch_bounds__(256) void scan1_kernel(
    const int* __restrict__ hist,
    int* __restrict__ row_part,
    int* __restrict__ bsum)
{
    __shared__ int s[256];
    int tid = threadIdx.x;
    int idx = blockIdx.x * 256 + tid;
    int val = (idx < N_NODES) ? hist[idx] : 0;
    s[tid] = val;
    __syncthreads();
    #pragma unroll
    for (int off = 1; off < 256; off <<= 1) {
        int t = (tid >= off) ? s[tid - off] : 0;
        __syncthreads();
        s[tid] += t;
        __syncthreads();
    }
    if (idx < N_NODES) row_part[idx] = s[tid] - val;
    if (tid == 255) bsum[blockIdx.x] = s[255];
}

// Kernel 3: exclusive scan of block sums (single block of 512).
__global__ __launch_bounds__(512) void scan2_kernel(
    const int* __restrict__ bsum,
    int* __restrict__ bsum_ex)
{
    __shared__ int s[512];
    int tid = threadIdx.x;
    int val = (tid < NBLK) ? bsum[tid] : 0;
    s[tid] = val;
    __syncthreads();
    #pragma unroll
    for (int off = 1; off < 512; off <<= 1) {
        int t = (tid >= off) ? s[tid - off] : 0;
        __syncthreads();
        s[tid] += t;
        __syncthreads();
    }
    bsum_ex[tid] = s[tid] - val;
}

// Kernel 4: scatter edge ids into CSR order. Minimal 4 B random writes;
// rank pass merged via atomic cursor. 2 edges/thread.
__global__ __launch_bounds__(256) void perm_kernel(
    const int* __restrict__ edge_index,
    const int* __restrict__ row_part,
    const int* __restrict__ bsum_ex,
    int* __restrict__ cursor,
    int* __restrict__ perm)
{
    int i = blockIdx.x * 256 + threadIdx.x;
    if (i >= N_EDGES / 2) return;
    int2 d = *(const int2*)(edge_index + N_EDGES + 2 * i);
    int slot0 = row_part[d.x] + bsum_ex[d.x >> 8] + atomicAdd(cursor + d.x, 1);
    perm[slot0] = 2 * i;
    int slot1 = row_part[d.y] + bsum_ex[d.y >> 8] + atomicAdd(cursor + d.y, 1);
    perm[slot1] = 2 * i + 1;
}

// ---------------------------------------------------------------------------
// Kernel 5 (fused gather + node): 5 threads per node accumulate the 80
// outer-product components in registers, contract with LDS-staged weights,
// reduce partials through padded LDS; wave 0 adds root+bias, writes out,
// and reduces batch stats. No S array round-trip.
// Per edge: 1 seq perm read + ONE random 32 B line (P) + one random v line.
// ---------------------------------------------------------------------------
__global__ __launch_bounds__(320) void gather_fused_kernel(
    const float* __restrict__ v,
    const float4* __restrict__ P,
    const int* __restrict__ perm,
    const int* __restrict__ hist,
    const int* __restrict__ row_part,
    const int* __restrict__ bsum_ex,
    const float* __restrict__ enet_w,
    const float* __restrict__ enet_b,
    const float* __restrict__ root,
    const float* __restrict__ bias,
    float* __restrict__ out,
    float* __restrict__ stats)
{
    __shared__ float wlds[5][260];    // [t][i*16+o], padded stride 260
    __shared__ float red[320][17];    // per-thread 16 partials, padded

    // stage weights: wlds[0] = enet_b, wlds[k] = enet_w[:, k-1]
    for (int i = threadIdx.x; i < 1280; i += 320) {
        int t = i >> 8, j = i & 255;
        wlds[t][j] = (t == 0) ? enet_b[j] : enet_w[j * 4 + (t - 1)];
    }

    int g = threadIdx.x / 5;          // local node
    int t = threadIdx.x % 5;          // component (0 = const, 1..4 = ef)
    int n = blockIdx.x * 64 + g;

    float acc[16];
    #pragma unroll
    for (int i = 0; i < 16; ++i) acc[i] = 0.0f;

    int deg = 0, start = 0;
    if (n < N_NODES) {
        start = row_part[n] + bsum_ex[n >> 8];
        deg = hist[n];
    }

    const int* pp = perm + start;
    int j = 0;
    for (; j + 2 <= deg; j += 2) {            // unroll x2 for load ILP
        int e0 = pp[j], e1 = pp[j + 1];
        float4 ef0 = P[(size_t)2 * e0];
        float4 sp0 = P[(size_t)2 * e0 + 1];
        float4 ef1 = P[(size_t)2 * e1];
        float4 sp1 = P[(size_t)2 * e1 + 1];
        int s0 = __float_as_int(sp0.x);
        int s1 = __float_as_int(sp1.x);
        float c0 = (t == 0) ? 1.0f : (t == 1) ? ef0.x : (t == 2) ? ef0.y
                 : (t == 3) ? ef0.z : ef0.w;
        float c1 = (t == 0) ? 1.0f : (t == 1) ? ef1.x : (t == 2) ? ef1.y
                 : (t == 3) ? ef1.z : ef1.w;
        const float4* v0 = (const float4*)(v + (size_t)s0 * 16);
        const float4* v1 = (const float4*)(v + (size_t)s1 * 16);
        #pragma unroll
        for (int i = 0; i < 4; ++i) {
            float4 a = v0[i], b = v1[i];
            acc[4*i+0] = fmaf(c0, a.x, fmaf(c1, b.x, acc[4*i+0]));
            acc[4*i+1] = fmaf(c0, a.y, fmaf(c1, b.y, acc[4*i+1]));
            acc[4*i+2] = fmaf(c0, a.z, fmaf(c1, b.z, acc[4*i+2]));
            acc[4*i+3] = fmaf(c0, a.w, fmaf(c1, b.w, acc[4*i+3]));
        }
    }
    if (j < deg) {
        int e0 = pp[j];
        float4 ef0 = P[(size_t)2 * e0];
        float4 sp0 = P[(size_t)2 * e0 + 1];
        int s0 = __float_as_int(sp0.x);
        float c0 = (t == 0) ? 1.0f : (t == 1) ? ef0.x : (t == 2) ? ef0.y
                 : (t == 3) ? ef0.z : ef0.w;
        const float4* v0 = (const float4*)(v + (size_t)s0 * 16);
        #pragma unroll
        for (int i = 0; i < 4; ++i) {
            float4 a = v0[i];
            acc[4*i+0] = fmaf(c0, a.x, acc[4*i+0]);
            acc[4*i+1] = fmaf(c0, a.y, acc[4*i+1]);
            acc[4*i+2] = fmaf(c0, a.z, acc[4*i+2]);
            acc[4*i+3] = fmaf(c0, a.w, acc[4*i+3]);
        }
    }

    __syncthreads();   // wlds ready; everyone reaches here (no early return)

    // partial contraction: part_t[o] = sum_i acc[i] * w_t[i][o]
    #pragma unroll
    for (int o = 0; o < 16; ++o) {
        float a = 0.0f;
        #pragma unroll
        for (int i = 0; i < 16; ++i)
            a = fmaf(acc[i], wlds[t][i * 16 + o], a);
        red[threadIdx.x][o] = a;
    }
    __syncthreads();

    // epilogue: wave 0 handles all 64 nodes of the block
    if (threadIdx.x < 64) {
        int l = threadIdx.x;
        int nn = blockIdx.x * 64 + l;
        float val[16];
        if (nn < N_NODES) {
            float scale = 1.0f / fmaxf((float)hist[nn], 1.0f);
            float vn[16];
            #pragma unroll
            for (int i = 0; i < 4; ++i) {
                float4 tv = *(const float4*)(v + (size_t)nn * 16 + i * 4);
                vn[4*i+0] = tv.x; vn[4*i+1] = tv.y;
                vn[4*i+2] = tv.z; vn[4*i+3] = tv.w;
            }
            #pragma unroll
            for (int o = 0; o < 16; ++o) {
                float s = red[l*5+0][o] + red[l*5+1][o] + red[l*5+2][o]
                        + red[l*5+3][o] + red[l*5+4][o];
                float a = fmaf(s, scale, bias[o]);
                #pragma unroll
                for (int i = 0; i < 16; ++i)
                    a = fmaf(vn[i], root[i * 16 + o], a);
                val[o] = a;
            }
            #pragma unroll
            for (int i = 0; i < 4; ++i)
                *(float4*)(out + (size_t)nn * 16 + i * 4) =
                    make_float4(val[4*i+0], val[4*i+1], val[4*i+2], val[4*i+3]);
        } else {
            #pragma unroll
            for (int o = 0; o < 16; ++o) val[o] = 0.0f;
        }

        // batch-stat reduction across the 64 lanes of wave 0
        #pragma unroll
        for (int o = 0; o < 16; ++o) {
            float a = val[o];
            float b = a * a;
            #pragma unroll
            for (int m = 1; m < 64; m <<= 1) {
                a += __shfl_xor(a, m, 64);
                b += __shfl_xor(b, m, 64);
            }
            if (threadIdx.x == 0) {
                unsafeAtomicAdd(stats + o, a);
                unsafeAtomicAdd(stats + 16 + o, b);
            }
        }
    }
}

// Kernel 6: BatchNorm (batch stats) + LeakyReLU, in place, float4-vectorized.
__global__ __launch_bounds__(256) void final_kernel(
    float* __restrict__ out,
    const float* __restrict__ stats,
    const float* __restrict__ gamma,
    const float* __restrict__ beta)
{
    int idx = blockIdx.x * 256 + threadIdx.x;      // float4 index
    if (idx >= N_NODES * 4) return;
    int o0 = (idx & 3) << 2;
    const float invN = 1.0f / (float)N_NODES;
    float4 x = *((const float4*)out + idx);
    float xs[4] = {x.x, x.y, x.z, x.w};
    float r[4];
    #pragma unroll
    for (int u = 0; u < 4; ++u) {
        int o = o0 + u;
        float mu = stats[o] * invN;
        float var = fmaxf(stats[16 + o] * invN - mu * mu, 0.0f);
        float y = fmaf(gamma[o] * (xs[u] - mu), rsqrtf(var + EPS), beta[o]);
        r[u] = (y >= 0.0f) ? y : SLOPE * y;
    }
    *((float4*)out + idx) = make_float4(r[0], r[1], r[2], r[3]);
}

extern "C" void kernel_launch(void* const* d_in, const int* in_sizes, int n_in,
                              void* d_out, int out_size, void* d_ws, size_t ws_size,
                              hipStream_t stream)
{
    const float* v = (const float*)d_in[0];
    const float* e = (const float*)d_in[1];
    const int* edge_index = (const int*)d_in[2];
    const float* enet_w = (const float*)d_in[3];
    const float* enet_b = (const float*)d_in[4];
    const float* root = (const float*)d_in[5];
    const float* bias = (const float*)d_in[6];
    const float* gamma = (const float*)d_in[7];
    const float* beta = (const float*)d_in[8];
    float* out = (float*)d_out;

    char* ws = (char*)d_ws;
    float4* P        = (float4*)ws;                 ws += (size_t)N_EDGES * 32;
    int*    perm     = (int*)ws;                    ws += (size_t)N_EDGES * 4;
    int*    hist     = (int*)ws;                    ws += (size_t)N_NODES * 4;
    int*    cursor   = (int*)ws;                    ws += (size_t)N_NODES * 4;
    float*  stats    = (float*)ws;                  ws += 32 * 4;
    int*    row_part = (int*)ws;                    ws += (size_t)N_NODES * 4;
    int*    bsum     = (int*)ws;                    ws += 512 * 4;
    int*    bsum_ex  = (int*)ws;

    // zero hist + cursor + stats (contiguous)
    hipMemsetAsync(hist, 0, (size_t)N_NODES * 4 * 2 + 32 * 4, stream);

    pack_count_kernel<<<(N_EDGES / 2 + 255) / 256, 256, 0, stream>>>(
        e, edge_index, hist, P);
    scan1_kernel<<<NBLK, 256, 0, stream>>>(hist, row_part, bsum);
    scan2_kernel<<<1, 512, 0, stream>>>(bsum, bsum_ex);
    perm_kernel<<<(N_EDGES / 2 + 255) / 256, 256, 0, stream>>>(
        edge_index, row_part, bsum_ex, cursor, perm);
    gather_fused_kernel<<<GBLK, 320, 0, stream>>>(
        v, P, perm, hist, row_part, bsum_ex,
        enet_w, enet_b, root, bias, out, stats);
    final_kernel<<<(N_NODES * 4 + 255) / 256, 256, 0, stream>>>(
        out, stats, gamma, beta);
}

// Round 3
// 271.889 us; speedup vs baseline: 1.9766x; 1.9766x over previous
//
#include <hip/hip_runtime.h>

#define N_NODES 100000
#define N_EDGES 1000000
#define EPS 1e-5f
#define SLOPE 0.01f
#define NBLK 391   // ceil(N_NODES/256)
#define GBLK 1563  // ceil(N_NODES/64): 64 nodes/block, 5 threads/node, 320/block

// ---------------------------------------------------------------------------
// ws layout:
//   S        : N*80 floats (32 MB)  per-node aggregated outer products
//   perm     : E ints   (4 MB)      edge id in CSR(dst) order
//   hist     : N ints   [zeroed]    in-degree
//   cursor   : N ints   [zeroed]    scatter cursor
//   stats    : 32 floats[zeroed]    sum[16], sumsq[16]
//   row_part : N ints
//   bsum     : 512 ints
//   bsum_ex  : 512 ints
// ---------------------------------------------------------------------------

// Kernel 1: in-degree histogram (4 edges/thread, int4 loads).
__global__ __launch_bounds__(256) void count_kernel(
    const int* __restrict__ edge_index,
    int* __restrict__ hist)
{
    int i = blockIdx.x * 256 + threadIdx.x;
    if (i >= N_EDGES / 4) return;
    int4 d = *(const int4*)(edge_index + N_EDGES + i * 4);
    atomicAdd(hist + d.x, 1);
    atomicAdd(hist + d.y, 1);
    atomicAdd(hist + d.z, 1);
    atomicAdd(hist + d.w, 1);
}

// Kernel 2: block-local exclusive scan of hist + block sums.
__global__ __launch_bounds__(256) void scan1_kernel(
    const int* __restrict__ hist,
    int* __restrict__ row_part,
    int* __restrict__ bsum)
{
    __shared__ int s[256];
    int tid = threadIdx.x;
    int idx = blockIdx.x * 256 + tid;
    int val = (idx < N_NODES) ? hist[idx] : 0;
    s[tid] = val;
    __syncthreads();
    #pragma unroll
    for (int off = 1; off < 256; off <<= 1) {
        int t = (tid >= off) ? s[tid - off] : 0;
        __syncthreads();
        s[tid] += t;
        __syncthreads();
    }
    if (idx < N_NODES) row_part[idx] = s[tid] - val;
    if (tid == 255) bsum[blockIdx.x] = s[255];
}

// Kernel 3: exclusive scan of block sums (single block of 512).
__global__ __launch_bounds__(512) void scan2_kernel(
    const int* __restrict__ bsum,
    int* __restrict__ bsum_ex)
{
    __shared__ int s[512];
    int tid = threadIdx.x;
    int val = (tid < NBLK) ? bsum[tid] : 0;
    s[tid] = val;
    __syncthreads();
    #pragma unroll
    for (int off = 1; off < 512; off <<= 1) {
        int t = (tid >= off) ? s[tid - off] : 0;
        __syncthreads();
        s[tid] += t;
        __syncthreads();
    }
    bsum_ex[tid] = s[tid] - val;
}

// Kernel 4: scatter edge ids into CSR order; rank merged via atomic cursor.
// 4 B random writes land in L2/L3 (perm is 4 MB) -> no write amplification.
__global__ __launch_bounds__(256) void perm_kernel(
    const int* __restrict__ edge_index,
    const int* __restrict__ row_part,
    const int* __restrict__ bsum_ex,
    int* __restrict__ cursor,
    int* __restrict__ perm)
{
    int i = blockIdx.x * 256 + threadIdx.x;
    if (i >= N_EDGES / 2) return;
    int2 d = *(const int2*)(edge_index + N_EDGES + 2 * i);
    int slot0 = row_part[d.x] + bsum_ex[d.x >> 8] + atomicAdd(cursor + d.x, 1);
    perm[slot0] = 2 * i;
    int slot1 = row_part[d.y] + bsum_ex[d.y >> 8] + atomicAdd(cursor + d.y, 1);
    perm[slot1] = 2 * i + 1;
}

// ---------------------------------------------------------------------------
// Kernel 5: S[n] = sum over incoming edges of outer(v[src], [1, ef]).
// 5 threads per node: thread t accumulates component t (16 floats).
// Latency-bound -> unroll x4: issue all 8 random loads (4 src + 4 ef) per
// chunk before consuming, ~4x outstanding HBM loads per thread.
// ---------------------------------------------------------------------------
__global__ __launch_bounds__(320) void gather_s_kernel(
    const float* __restrict__ v,
    const float* __restrict__ efeat,
    const int* __restrict__ edge_index,
    const int* __restrict__ perm,
    const int* __restrict__ hist,
    const int* __restrict__ row_part,
    const int* __restrict__ bsum_ex,
    float* __restrict__ S)
{
    int tid = blockIdx.x * 320 + threadIdx.x;
    int n = tid / 5;
    int t = tid % 5;
    if (n >= N_NODES) return;

    int start = row_part[n] + bsum_ex[n >> 8];
    int deg = hist[n];

    float acc[16];
    #pragma unroll
    for (int i = 0; i < 16; ++i) acc[i] = 0.0f;

    const int* pp = perm + start;
    int j = 0;
    for (; j + 4 <= deg; j += 4) {
        int e0 = pp[j], e1 = pp[j + 1], e2 = pp[j + 2], e3 = pp[j + 3];
        // 8 independent random loads in flight
        int s0 = edge_index[e0];
        int s1 = edge_index[e1];
        int s2 = edge_index[e2];
        int s3 = edge_index[e3];
        float4 f0 = *(const float4*)(efeat + (size_t)e0 * 4);
        float4 f1 = *(const float4*)(efeat + (size_t)e1 * 4);
        float4 f2 = *(const float4*)(efeat + (size_t)e2 * 4);
        float4 f3 = *(const float4*)(efeat + (size_t)e3 * 4);
        float c0 = (t == 0) ? 1.0f : (t == 1) ? f0.x : (t == 2) ? f0.y
                 : (t == 3) ? f0.z : f0.w;
        float c1 = (t == 0) ? 1.0f : (t == 1) ? f1.x : (t == 2) ? f1.y
                 : (t == 3) ? f1.z : f1.w;
        float c2 = (t == 0) ? 1.0f : (t == 1) ? f2.x : (t == 2) ? f2.y
                 : (t == 3) ? f2.z : f2.w;
        float c3 = (t == 0) ? 1.0f : (t == 1) ? f3.x : (t == 2) ? f3.y
                 : (t == 3) ? f3.z : f3.w;
        const float4* v0 = (const float4*)(v + (size_t)s0 * 16);
        const float4* v1 = (const float4*)(v + (size_t)s1 * 16);
        const float4* v2 = (const float4*)(v + (size_t)s2 * 16);
        const float4* v3 = (const float4*)(v + (size_t)s3 * 16);
        #pragma unroll
        for (int i = 0; i < 4; ++i) {
            float4 a = v0[i], b = v1[i], c = v2[i], d = v3[i];
            acc[4*i+0] = fmaf(c0, a.x, fmaf(c1, b.x,
                         fmaf(c2, c.x, fmaf(c3, d.x, acc[4*i+0]))));
            acc[4*i+1] = fmaf(c0, a.y, fmaf(c1, b.y,
                         fmaf(c2, c.y, fmaf(c3, d.y, acc[4*i+1]))));
            acc[4*i+2] = fmaf(c0, a.z, fmaf(c1, b.z,
                         fmaf(c2, c.z, fmaf(c3, d.z, acc[4*i+2]))));
            acc[4*i+3] = fmaf(c0, a.w, fmaf(c1, b.w,
                         fmaf(c2, c.w, fmaf(c3, d.w, acc[4*i+3]))));
        }
    }
    for (; j < deg; ++j) {
        int e0 = pp[j];
        int s0 = edge_index[e0];
        float4 f0 = *(const float4*)(efeat + (size_t)e0 * 4);
        float c0 = (t == 0) ? 1.0f : (t == 1) ? f0.x : (t == 2) ? f0.y
                 : (t == 3) ? f0.z : f0.w;
        const float4* v0 = (const float4*)(v + (size_t)s0 * 16);
        #pragma unroll
        for (int i = 0; i < 4; ++i) {
            float4 a = v0[i];
            acc[4*i+0] = fmaf(c0, a.x, acc[4*i+0]);
            acc[4*i+1] = fmaf(c0, a.y, acc[4*i+1]);
            acc[4*i+2] = fmaf(c0, a.z, acc[4*i+2]);
            acc[4*i+3] = fmaf(c0, a.w, acc[4*i+3]);
        }
    }

    float* sp = S + (size_t)n * 80 + t * 16;
    #pragma unroll
    for (int i = 0; i < 4; ++i)
        *(float4*)(sp + i * 4) = make_float4(acc[4*i+0], acc[4*i+1],
                                             acc[4*i+2], acc[4*i+3]);
}

// ---------------------------------------------------------------------------
// Kernel 6: per-node: summed = S0*B + sum_k Sk*Wk; mean + root + bias -> out;
// per-column sum/sumsq reduction into stats. Weights are wave-uniform -> SGPR.
// ---------------------------------------------------------------------------
__global__ __launch_bounds__(256) void node_kernel(
    const float* __restrict__ v,
    const float* __restrict__ S,
    const int* __restrict__ hist,
    const float* __restrict__ enet_w,
    const float* __restrict__ enet_b,
    const float* __restrict__ root,
    const float* __restrict__ bias,
    float* __restrict__ out,
    float* __restrict__ stats)
{
    int n = blockIdx.x * 256 + threadIdx.x;
    bool active = (n < N_NODES);

    float val[16];
    if (active) {
        float s[80];
        #pragma unroll
        for (int i = 0; i < 20; ++i) {
            float4 tv = *(const float4*)(S + (size_t)n * 80 + i * 4);
            s[i*4+0] = tv.x; s[i*4+1] = tv.y; s[i*4+2] = tv.z; s[i*4+3] = tv.w;
        }
        float vn[16];
        #pragma unroll
        for (int i = 0; i < 4; ++i) {
            float4 tv = *(const float4*)(v + (size_t)n * 16 + i * 4);
            vn[i*4+0] = tv.x; vn[i*4+1] = tv.y; vn[i*4+2] = tv.z; vn[i*4+3] = tv.w;
        }
        float scale = 1.0f / fmaxf((float)hist[n], 1.0f);

        #pragma unroll
        for (int o = 0; o < 16; ++o) {
            float a = 0.0f;
            #pragma unroll
            for (int i = 0; i < 16; ++i) {
                a = fmaf(s[i], enet_b[i * 16 + o], a);           // S0 * B
                #pragma unroll
                for (int k = 0; k < 4; ++k)
                    a = fmaf(s[16 + k * 16 + i],
                             enet_w[(i * 16 + o) * 4 + k], a);   // Sk * Wk
            }
            a = fmaf(a, scale, bias[o]);
            #pragma unroll
            for (int i = 0; i < 16; ++i)
                a = fmaf(vn[i], root[i * 16 + o], a);
            val[o] = a;
        }
        #pragma unroll
        for (int i = 0; i < 4; ++i)
            *(float4*)(out + (size_t)n * 16 + i * 4) =
                make_float4(val[i*4+0], val[i*4+1], val[i*4+2], val[i*4+3]);
    } else {
        #pragma unroll
        for (int o = 0; o < 16; ++o) val[o] = 0.0f;
    }

    // wave butterfly + LDS reduction of sum / sumsq per column
    float ssum[16], ssq[16];
    #pragma unroll
    for (int o = 0; o < 16; ++o) {
        float a = val[o];
        float b = a * a;
        #pragma unroll
        for (int m = 1; m < 64; m <<= 1) {
            a += __shfl_xor(a, m, 64);
            b += __shfl_xor(b, m, 64);
        }
        ssum[o] = a; ssq[o] = b;
    }
    __shared__ float part[4][32];
    int wave = threadIdx.x >> 6;
    int lane = threadIdx.x & 63;
    if (lane == 0) {
        #pragma unroll
        for (int o = 0; o < 16; ++o) {
            part[wave][o] = ssum[o];
            part[wave][16 + o] = ssq[o];
        }
    }
    __syncthreads();
    if (threadIdx.x < 32) {
        float t = part[0][threadIdx.x] + part[1][threadIdx.x] +
                  part[2][threadIdx.x] + part[3][threadIdx.x];
        unsafeAtomicAdd(stats + threadIdx.x, t);
    }
}

// Kernel 7: BatchNorm (batch stats) + LeakyReLU, in place, float4-vectorized.
__global__ __launch_bounds__(256) void final_kernel(
    float* __restrict__ out,
    const float* __restrict__ stats,
    const float* __restrict__ gamma,
    const float* __restrict__ beta)
{
    int idx = blockIdx.x * 256 + threadIdx.x;      // float4 index
    if (idx >= N_NODES * 4) return;
    int o0 = (idx & 3) << 2;
    const float invN = 1.0f / (float)N_NODES;
    float4 x = *((const float4*)out + idx);
    float xs[4] = {x.x, x.y, x.z, x.w};
    float r[4];
    #pragma unroll
    for (int u = 0; u < 4; ++u) {
        int o = o0 + u;
        float mu = stats[o] * invN;
        float var = fmaxf(stats[16 + o] * invN - mu * mu, 0.0f);
        float y = fmaf(gamma[o] * (xs[u] - mu), rsqrtf(var + EPS), beta[o]);
        r[u] = (y >= 0.0f) ? y : SLOPE * y;
    }
    *((float4*)out + idx) = make_float4(r[0], r[1], r[2], r[3]);
}

extern "C" void kernel_launch(void* const* d_in, const int* in_sizes, int n_in,
                              void* d_out, int out_size, void* d_ws, size_t ws_size,
                              hipStream_t stream)
{
    const float* v = (const float*)d_in[0];
    const float* e = (const float*)d_in[1];
    const int* edge_index = (const int*)d_in[2];
    const float* enet_w = (const float*)d_in[3];
    const float* enet_b = (const float*)d_in[4];
    const float* root = (const float*)d_in[5];
    const float* bias = (const float*)d_in[6];
    const float* gamma = (const float*)d_in[7];
    const float* beta = (const float*)d_in[8];
    float* out = (float*)d_out;

    char* ws = (char*)d_ws;
    float* S        = (float*)ws;                   ws += (size_t)N_NODES * 80 * 4;
    int*   perm     = (int*)ws;                     ws += (size_t)N_EDGES * 4;
    int*   hist     = (int*)ws;                     ws += (size_t)N_NODES * 4;
    int*   cursor   = (int*)ws;                     ws += (size_t)N_NODES * 4;
    float* stats    = (float*)ws;                   ws += 32 * 4;
    int*   row_part = (int*)ws;                     ws += (size_t)N_NODES * 4;
    int*   bsum     = (int*)ws;                     ws += 512 * 4;
    int*   bsum_ex  = (int*)ws;

    // zero hist + cursor + stats (contiguous)
    hipMemsetAsync(hist, 0, (size_t)N_NODES * 4 * 2 + 32 * 4, stream);

    count_kernel<<<(N_EDGES / 4 + 255) / 256, 256, 0, stream>>>(edge_index, hist);
    scan1_kernel<<<NBLK, 256, 0, stream>>>(hist, row_part, bsum);
    scan2_kernel<<<1, 512, 0, stream>>>(bsum, bsum_ex);
    perm_kernel<<<(N_EDGES / 2 + 255) / 256, 256, 0, stream>>>(
        edge_index, row_part, bsum_ex, cursor, perm);
    gather_s_kernel<<<GBLK, 320, 0, stream>>>(
        v, e, edge_index, perm, hist, row_part, bsum_ex, S);
    node_kernel<<<NBLK, 256, 0, stream>>>(
        v, S, hist, enet_w, enet_b, root, bias, out, stats);
    final_kernel<<<(N_NODES * 4 + 255) / 256, 256, 0, stream>>>(
        out, stats, gamma, beta);
}

// Round 4
// 234.041 us; speedup vs baseline: 2.2963x; 1.1617x over previous
//
#include <hip/hip_runtime.h>

#define N_NODES 100000
#define N_EDGES 1000000
#define EPS 1e-5f
#define SLOPE 0.01f
#define NBLK 391   // ceil(N_NODES/256)

// ---------------------------------------------------------------------------
// ws layout:
//   P        : E * 32 B (32 MB)  {float4 ef; int src; pad} in CSR(dst) order
//   hist     : N ints   [zeroed] in-degree
//   cursor   : N ints   [zeroed] scatter cursor
//   stats    : 32 floats[zeroed] sum[16], sumsq[16]
//   row_part : N ints
//   bsum     : 512 ints
//   bsum_ex  : 512 ints
// Key measured facts driving this design (r1/r3 counters):
//   - random 4 B scatter write costs a full 64 B line at HBM (74 MB for 4 MB)
//     -> scattering 32 B costs the SAME as 4 B: scatter the whole payload.
//   - gather was at the random-line-fetch ceiling (158 MB FETCH, unroll-
//     insensitive) -> make gather sequential instead of adding MLP.
// ---------------------------------------------------------------------------

// Kernel 1: in-degree histogram (4 edges/thread, int4 loads).
__global__ __launch_bounds__(256) void count_kernel(
    const int* __restrict__ edge_index,
    int* __restrict__ hist)
{
    int i = blockIdx.x * 256 + threadIdx.x;
    if (i >= N_EDGES / 4) return;
    int4 d = *(const int4*)(edge_index + N_EDGES + i * 4);
    atomicAdd(hist + d.x, 1);
    atomicAdd(hist + d.y, 1);
    atomicAdd(hist + d.z, 1);
    atomicAdd(hist + d.w, 1);
}

// Kernel 2: block-local exclusive scan of hist + block sums.
__global__ __launch_bounds__(256) void scan1_kernel(
    const int* __restrict__ hist,
    int* __restrict__ row_part,
    int* __restrict__ bsum)
{
    __shared__ int s[256];
    int tid = threadIdx.x;
    int idx = blockIdx.x * 256 + tid;
    int val = (idx < N_NODES) ? hist[idx] : 0;
    s[tid] = val;
    __syncthreads();
    #pragma unroll
    for (int off = 1; off < 256; off <<= 1) {
        int t = (tid >= off) ? s[tid - off] : 0;
        __syncthreads();
        s[tid] += t;
        __syncthreads();
    }
    if (idx < N_NODES) row_part[idx] = s[tid] - val;
    if (tid == 255) bsum[blockIdx.x] = s[255];
}

// Kernel 3: exclusive scan of block sums (single block of 512).
__global__ __launch_bounds__(512) void scan2_kernel(
    const int* __restrict__ bsum,
    int* __restrict__ bsum_ex)
{
    __shared__ int s[512];
    int tid = threadIdx.x;
    int val = (tid < NBLK) ? bsum[tid] : 0;
    s[tid] = val;
    __syncthreads();
    #pragma unroll
    for (int off = 1; off < 512; off <<= 1) {
        int t = (tid >= off) ? s[tid - off] : 0;
        __syncthreads();
        s[tid] += t;
        __syncthreads();
    }
    bsum_ex[tid] = s[tid] - val;
}

// ---------------------------------------------------------------------------
// Kernel 4: scatter the FULL edge payload {ef, src} into CSR(dst) slot order.
// One aligned 32 B random write per edge = one dirty line, same HBM cost as
// the old 4 B perm scatter (measured ~64-74 B/edge either way), but it buys a
// fully-sequential aggregation pass. Rank merged via atomic cursor.
// ---------------------------------------------------------------------------
__global__ __launch_bounds__(256) void scatter_kernel(
    const float* __restrict__ efeat,
    const int* __restrict__ edge_index,
    const int* __restrict__ row_part,
    const int* __restrict__ bsum_ex,
    int* __restrict__ cursor,
    float4* __restrict__ P)
{
    int eid = blockIdx.x * 256 + threadIdx.x;
    if (eid >= N_EDGES) return;
    int src = edge_index[eid];
    int dst = edge_index[N_EDGES + eid];
    float4 ef = *(const float4*)(efeat + (size_t)eid * 4);
    int slot = row_part[dst] + bsum_ex[dst >> 8] + atomicAdd(cursor + dst, 1);
    P[(size_t)2 * slot]     = ef;
    P[(size_t)2 * slot + 1] = make_float4(__int_as_float(src), 0.f, 0.f, 0.f);
}

// ---------------------------------------------------------------------------
// Kernel 5 (fused gather + node): 1 thread per node. Reads its contiguous
// CSR payload run sequentially (32 B/edge), v[src] random but L2-resident.
// acc[5][16] outer-products in registers, then the weight contraction,
// root + bias, out write, and batch-stat reduction. No LDS reduction, no
// barrier in the hot loop (round-2 lesson), no S round-trip.
// ---------------------------------------------------------------------------
__global__ __launch_bounds__(256) void gather_node_kernel(
    const float* __restrict__ v,
    const float4* __restrict__ P,
    const int* __restrict__ hist,
    const int* __restrict__ row_part,
    const int* __restrict__ bsum_ex,
    const float* __restrict__ enet_w,
    const float* __restrict__ enet_b,
    const float* __restrict__ root,
    const float* __restrict__ bias,
    float* __restrict__ out,
    float* __restrict__ stats)
{
    int n = blockIdx.x * 256 + threadIdx.x;
    bool active = (n < N_NODES);

    float acc[80];
    #pragma unroll
    for (int i = 0; i < 80; ++i) acc[i] = 0.0f;

    int deg = 0, start = 0;
    if (active) {
        start = row_part[n] + bsum_ex[n >> 8];
        deg = hist[n];
    }

    const float4* pp = P + (size_t)2 * start;
    for (int j = 0; j < deg; ++j) {
        float4 ef = pp[2 * j];
        float4 sp = pp[2 * j + 1];
        int src = __float_as_int(sp.x);
        const float4* vr = (const float4*)(v + (size_t)src * 16);
        #pragma unroll
        for (int i = 0; i < 4; ++i) {
            float4 a = vr[i];
            acc[     i*4+0] += a.x;                    // c = 1
            acc[     i*4+1] += a.y;
            acc[     i*4+2] += a.z;
            acc[     i*4+3] += a.w;
            acc[16 + i*4+0] = fmaf(ef.x, a.x, acc[16 + i*4+0]);
            acc[16 + i*4+1] = fmaf(ef.x, a.y, acc[16 + i*4+1]);
            acc[16 + i*4+2] = fmaf(ef.x, a.z, acc[16 + i*4+2]);
            acc[16 + i*4+3] = fmaf(ef.x, a.w, acc[16 + i*4+3]);
            acc[32 + i*4+0] = fmaf(ef.y, a.x, acc[32 + i*4+0]);
            acc[32 + i*4+1] = fmaf(ef.y, a.y, acc[32 + i*4+1]);
            acc[32 + i*4+2] = fmaf(ef.y, a.z, acc[32 + i*4+2]);
            acc[32 + i*4+3] = fmaf(ef.y, a.w, acc[32 + i*4+3]);
            acc[48 + i*4+0] = fmaf(ef.z, a.x, acc[48 + i*4+0]);
            acc[48 + i*4+1] = fmaf(ef.z, a.y, acc[48 + i*4+1]);
            acc[48 + i*4+2] = fmaf(ef.z, a.z, acc[48 + i*4+2]);
            acc[48 + i*4+3] = fmaf(ef.z, a.w, acc[48 + i*4+3]);
            acc[64 + i*4+0] = fmaf(ef.w, a.x, acc[64 + i*4+0]);
            acc[64 + i*4+1] = fmaf(ef.w, a.y, acc[64 + i*4+1]);
            acc[64 + i*4+2] = fmaf(ef.w, a.z, acc[64 + i*4+2]);
            acc[64 + i*4+3] = fmaf(ef.w, a.w, acc[64 + i*4+3]);
        }
    }

    float val[16];
    if (active) {
        float vn[16];
        #pragma unroll
        for (int i = 0; i < 4; ++i) {
            float4 tv = *(const float4*)(v + (size_t)n * 16 + i * 4);
            vn[4*i+0] = tv.x; vn[4*i+1] = tv.y;
            vn[4*i+2] = tv.z; vn[4*i+3] = tv.w;
        }
        float scale = 1.0f / fmaxf((float)deg, 1.0f);
        #pragma unroll
        for (int o = 0; o < 16; ++o) {
            float a = 0.0f;
            #pragma unroll
            for (int i = 0; i < 16; ++i) {
                a = fmaf(acc[i], enet_b[i * 16 + o], a);           // S0 * B
                #pragma unroll
                for (int k = 0; k < 4; ++k)
                    a = fmaf(acc[16 + k * 16 + i],
                             enet_w[(i * 16 + o) * 4 + k], a);     // Sk * Wk
            }
            a = fmaf(a, scale, bias[o]);
            #pragma unroll
            for (int i = 0; i < 16; ++i)
                a = fmaf(vn[i], root[i * 16 + o], a);
            val[o] = a;
        }
        #pragma unroll
        for (int i = 0; i < 4; ++i)
            *(float4*)(out + (size_t)n * 16 + i * 4) =
                make_float4(val[4*i+0], val[4*i+1], val[4*i+2], val[4*i+3]);
    } else {
        #pragma unroll
        for (int o = 0; o < 16; ++o) val[o] = 0.0f;
    }

    // wave butterfly + LDS reduction of sum / sumsq per column
    float ssum[16], ssq[16];
    #pragma unroll
    for (int o = 0; o < 16; ++o) {
        float a = val[o];
        float b = a * a;
        #pragma unroll
        for (int m = 1; m < 64; m <<= 1) {
            a += __shfl_xor(a, m, 64);
            b += __shfl_xor(b, m, 64);
        }
        ssum[o] = a; ssq[o] = b;
    }
    __shared__ float part[4][32];
    int wave = threadIdx.x >> 6;
    int lane = threadIdx.x & 63;
    if (lane == 0) {
        #pragma unroll
        for (int o = 0; o < 16; ++o) {
            part[wave][o] = ssum[o];
            part[wave][16 + o] = ssq[o];
        }
    }
    __syncthreads();
    if (threadIdx.x < 32) {
        float t = part[0][threadIdx.x] + part[1][threadIdx.x] +
                  part[2][threadIdx.x] + part[3][threadIdx.x];
        unsafeAtomicAdd(stats + threadIdx.x, t);
    }
}

// Kernel 6: BatchNorm (batch stats) + LeakyReLU, in place, float4-vectorized.
__global__ __launch_bounds__(256) void final_kernel(
    float* __restrict__ out,
    const float* __restrict__ stats,
    const float* __restrict__ gamma,
    const float* __restrict__ beta)
{
    int idx = blockIdx.x * 256 + threadIdx.x;      // float4 index
    if (idx >= N_NODES * 4) return;
    int o0 = (idx & 3) << 2;
    const float invN = 1.0f / (float)N_NODES;
    float4 x = *((const float4*)out + idx);
    float xs[4] = {x.x, x.y, x.z, x.w};
    float r[4];
    #pragma unroll
    for (int u = 0; u < 4; ++u) {
        int o = o0 + u;
        float mu = stats[o] * invN;
        float var = fmaxf(stats[16 + o] * invN - mu * mu, 0.0f);
        float y = fmaf(gamma[o] * (xs[u] - mu), rsqrtf(var + EPS), beta[o]);
        r[u] = (y >= 0.0f) ? y : SLOPE * y;
    }
    *((float4*)out + idx) = make_float4(r[0], r[1], r[2], r[3]);
}

extern "C" void kernel_launch(void* const* d_in, const int* in_sizes, int n_in,
                              void* d_out, int out_size, void* d_ws, size_t ws_size,
                              hipStream_t stream)
{
    const float* v = (const float*)d_in[0];
    const float* e = (const float*)d_in[1];
    const int* edge_index = (const int*)d_in[2];
    const float* enet_w = (const float*)d_in[3];
    const float* enet_b = (const float*)d_in[4];
    const float* root = (const float*)d_in[5];
    const float* bias = (const float*)d_in[6];
    const float* gamma = (const float*)d_in[7];
    const float* beta = (const float*)d_in[8];
    float* out = (float*)d_out;

    char* ws = (char*)d_ws;
    float4* P        = (float4*)ws;                 ws += (size_t)N_EDGES * 32;
    int*    hist     = (int*)ws;                    ws += (size_t)N_NODES * 4;
    int*    cursor   = (int*)ws;                    ws += (size_t)N_NODES * 4;
    float*  stats    = (float*)ws;                  ws += 32 * 4;
    int*    row_part = (int*)ws;                    ws += (size_t)N_NODES * 4;
    int*    bsum     = (int*)ws;                    ws += 512 * 4;
    int*    bsum_ex  = (int*)ws;

    // zero hist + cursor + stats (contiguous)
    hipMemsetAsync(hist, 0, (size_t)N_NODES * 4 * 2 + 32 * 4, stream);

    count_kernel<<<(N_EDGES / 4 + 255) / 256, 256, 0, stream>>>(edge_index, hist);
    scan1_kernel<<<NBLK, 256, 0, stream>>>(hist, row_part, bsum);
    scan2_kernel<<<1, 512, 0, stream>>>(bsum, bsum_ex);
    scatter_kernel<<<(N_EDGES + 255) / 256, 256, 0, stream>>>(
        e, edge_index, row_part, bsum_ex, cursor, P);
    gather_node_kernel<<<NBLK, 256, 0, stream>>>(
        v, P, hist, row_part, bsum_ex, enet_w, enet_b, root, bias, out, stats);
    final_kernel<<<(N_NODES * 4 + 255) / 256, 256, 0, stream>>>(
        out, stats, gamma, beta);
}